// Round 4
// baseline (1011.311 us; speedup 1.0000x reference)
//
#include <hip/hip_runtime.h>

// Sinkhorn, N=4096, D=2, P=1, eps=0.1, 50 iters — persistent cooperative kernel.
// u_i = eps*log_mu - eps*ln sum_j exp((v_j - C_ij)/eps); v symmetric with fresh u.
// Scaled space: arg2 = W_j - |RX_i - C0_j| - |RY_i - C1_j|, all values * log2(e)/eps.
//
// Round-4 changes vs round 3 (643 us, VALUBusy 47%, stall 3.4 us/phase):
//  - Flat flag barrier: block stores epoch to flags[bid] (no RMW tree = 3 MALL
//    round-trips); wave0 polls 256 flags (4 dwords/lane) + __all ballot.
//    Data-store -> __syncthreads (vmcnt drain) -> flag store gives ordering.
//  - Quad structure: 4-wave groups share 4 rows (RPW=4), each wave 1024 cols.
//    Halves LDS read traffic (192 KB/block/phase) vs round-3 pairs.
//  - Static column coords staged ONCE (64 KB LDS); per-phase stage = W only.

#define NPTS    4096
#define EPS_F   0.1f
#define S_L2E   14.426950408889634f     /* log2(e)/eps */
#define INV_SL  0.0693147180559945f     /* 1/S_L2E = eps*ln2 */
#define A_LOGMU (-0.8317725207f)        /* eps * ln(1/N + 1e-8) */
#define N_ITER  50
#define NBLK    256
#define TPB     1024
#define WPB     (TPB / 64)              /* 16 waves/block */
#define RPW     4                       /* rows per quad (4 waves share them) */
#define QCOLS   1024                    /* columns per wave within its quad */
#define NJT     (QCOLS / 256)           /* 4 j-tiles of 64 lanes x 4 cols */

typedef float f4u __attribute__((ext_vector_type(4), aligned(4)));

__device__ __forceinline__ float fexp2(float x) {
#if __has_builtin(__builtin_amdgcn_exp2f)
  return __builtin_amdgcn_exp2f(x);
#else
  float r;
  asm("v_exp_f32 %0, %1" : "=v"(r) : "v"(x));
  return r;
#endif
}

__device__ __forceinline__ float coh_load(const float* p) {
  return __hip_atomic_load(p, __ATOMIC_RELAXED, __HIP_MEMORY_SCOPE_AGENT);
}
__device__ __forceinline__ void coh_store(float* p, float x) {
  __hip_atomic_store(p, x, __ATOMIC_RELAXED, __HIP_MEMORY_SCOPE_AGENT);
}
__device__ __forceinline__ int coh_load_i(const int* p) {
  return __hip_atomic_load(p, __ATOMIC_RELAXED, __HIP_MEMORY_SCOPE_AGENT);
}
__device__ __forceinline__ void coh_store_i(int* p, int x) {
  __hip_atomic_store(p, x, __ATOMIC_RELAXED, __HIP_MEMORY_SCOPE_AGENT);
}

__device__ __forceinline__ float wave_sum64(float x) {
#pragma unroll
  for (int off = 32; off > 0; off >>= 1) x += __shfl_xor(x, off, 64);
  return x;
}

// Flat flag barrier. All ops sc0/sc1 (MALL = coherence point, no cache
// maintenance ever). First __syncthreads drains every wave's coherent data
// stores (compiler emits s_waitcnt vmcnt(0) before s_barrier), so the flag
// store — issued after it by the same block — is globally ordered after the
// block's u/v results. Wave 0 polls all 256 flags; others wait at the final
// __syncthreads.
__device__ __forceinline__ void grid_barrier(int* flags, int k, int tid) {
  __syncthreads();
  if (tid < 64) {
    if (tid == 0) coh_store_i(flags + blockIdx.x, k);
    const int b = tid * 4;
    bool ok;
    do {
      const int f0 = coh_load_i(flags + b + 0);
      const int f1 = coh_load_i(flags + b + 1);
      const int f2 = coh_load_i(flags + b + 2);
      const int f3 = coh_load_i(flags + b + 3);
      ok = (f0 >= k) & (f1 >= k) & (f2 >= k) & (f3 >= k);
    } while (!__all(ok));
  }
  __syncthreads();
}

// Per-phase stage: only the 4096 potentials (coherent), scaled, into LDS.
__device__ __forceinline__ void stageW(const float* __restrict__ win,
                                       float* __restrict__ sW, int tid) {
  const int c = tid * 4;
  const float w0 = coh_load(win + c + 0), w1 = coh_load(win + c + 1);
  const float w2 = coh_load(win + c + 2), w3 = coh_load(win + c + 3);
  float4 W;
  W.x = w0 * S_L2E; W.y = w1 * S_L2E; W.z = w2 * S_L2E; W.w = w3 * S_L2E;
  *(float4*)(sW + c) = W;
  __syncthreads();
}

// One half-iteration: quad (4 waves) shares RPW=4 rows; each wave covers
// QCOLS=1024 columns; tid<16 combine quad partials, log, coherent store.
__device__ __forceinline__ void phase(const float* __restrict__ rx,
                                      const float* __restrict__ ry,
                                      const float* __restrict__ sW,
                                      const float* __restrict__ sC0,
                                      const float* __restrict__ sC1,
                                      float (*sPart)[RPW],
                                      float* __restrict__ wout,
                                      int row0blk, int wv, int wq,
                                      int lane, int tid) {
  const int cb = wq * QCOLS + lane * 4;
  float acc[RPW];
#pragma unroll
  for (int r = 0; r < RPW; ++r) acc[r] = 0.f;
#pragma unroll
  for (int jt = 0; jt < NJT; ++jt) {
    const int j = cb + jt * 256;
    const float4 W  = *(const float4*)(sW + j);
    const float4 C0 = *(const float4*)(sC0 + j);
    const float4 C1 = *(const float4*)(sC1 + j);
#pragma unroll
    for (int r = 0; r < RPW; ++r) {
      const float a0 = (W.x - fabsf(rx[r] - C0.x)) - fabsf(ry[r] - C1.x);
      const float a1 = (W.y - fabsf(rx[r] - C0.y)) - fabsf(ry[r] - C1.y);
      const float a2 = (W.z - fabsf(rx[r] - C0.z)) - fabsf(ry[r] - C1.z);
      const float a3 = (W.w - fabsf(rx[r] - C0.w)) - fabsf(ry[r] - C1.w);
      acc[r] += (fexp2(a0) + fexp2(a1)) + (fexp2(a2) + fexp2(a3));
    }
  }
  float4 S;
  S.x = wave_sum64(acc[0]);
  S.y = wave_sum64(acc[1]);
  S.z = wave_sum64(acc[2]);
  S.w = wave_sum64(acc[3]);
  if (lane == 0) *(float4*)(&sPart[wv][0]) = S;
  __syncthreads();
  if (tid < 16) {                       // row-in-block = tid = quad*4 + r
    const int quad = tid >> 2, r = tid & 3;
    const float Ssum = ((sPart[quad * 4 + 0][r] + sPart[quad * 4 + 1][r]) +
                        (sPart[quad * 4 + 2][r] + sPart[quad * 4 + 3][r]));
    coh_store(wout + row0blk + tid, A_LOGMU - EPS_F * __logf(Ssum));
  }
}

__global__ void __launch_bounds__(TPB, 4)
sinkhorn_main(const float* __restrict__ x, const float* __restrict__ y,
              float* __restrict__ u, float* __restrict__ v,
              float* __restrict__ out, int* __restrict__ flags) {
  __shared__ float sW[NPTS];
  __shared__ float sYc0[NPTS], sYc1[NPTS];   // u-phase cols (y), static
  __shared__ float sXc0[NPTS], sXc1[NPTS];   // v-phase cols (x), static
  __shared__ float sPart[WPB][RPW];
  __shared__ float sCost[WPB];

  const int tid  = threadIdx.x;
  const int wv   = tid >> 6;
  const int lane = tid & 63;
  const int quad = wv >> 2;              // 4 quads of 4 waves
  const int wq   = wv & 3;               // wave index within quad
  const int row0blk = blockIdx.x * 16;   // 16 rows per block
  const int row0 = row0blk + quad * RPW; // this quad's rows

  // Static column coordinates, scaled, staged once (64 KB).
  {
    const int c = tid * 4;
    const float4 ya = ((const float4*)y)[(c >> 1) + 0];
    const float4 yb = ((const float4*)y)[(c >> 1) + 1];
    const float4 xa = ((const float4*)x)[(c >> 1) + 0];
    const float4 xb = ((const float4*)x)[(c >> 1) + 1];
    float4 t;
    t.x = ya.x * S_L2E; t.y = ya.z * S_L2E; t.z = yb.x * S_L2E; t.w = yb.z * S_L2E;
    *(float4*)(sYc0 + c) = t;
    t.x = ya.y * S_L2E; t.y = ya.w * S_L2E; t.z = yb.y * S_L2E; t.w = yb.w * S_L2E;
    *(float4*)(sYc1 + c) = t;
    t.x = xa.x * S_L2E; t.y = xa.z * S_L2E; t.z = xb.x * S_L2E; t.w = xb.z * S_L2E;
    *(float4*)(sXc0 + c) = t;
    t.x = xa.y * S_L2E; t.y = xa.w * S_L2E; t.z = xb.y * S_L2E; t.w = xb.w * S_L2E;
    *(float4*)(sXc1 + c) = t;
  }
  // (first stageW's __syncthreads covers these writes)

  float rxu[RPW], ryu[RPW], rxv[RPW], ryv[RPW];
#pragma unroll
  for (int r = 0; r < RPW; ++r) {
    const float2 xr = ((const float2*)x)[row0 + r];
    const float2 yr = ((const float2*)y)[row0 + r];
    rxu[r] = xr.x * S_L2E;  ryu[r] = xr.y * S_L2E;
    rxv[r] = yr.x * S_L2E;  ryv[r] = yr.y * S_L2E;
  }

  int k = 0;
  for (int it = 0; it < N_ITER; ++it) {
    stageW(v, sW, tid);                                     // win = v, cols = y
    phase(rxu, ryu, sW, sYc0, sYc1, sPart, u, row0blk, wv, wq, lane, tid);
    grid_barrier(flags, ++k, tid);
    stageW(u, sW, tid);                                     // win = u, cols = x
    phase(rxv, ryv, sW, sXc0, sXc1, sPart, v, row0blk, wv, wq, lane, tid);
    grid_barrier(flags, ++k, tid);
  }
  stageW(v, sW, tid);                                       // final v

  // ---- output: out[0]=cost, out[1..]=pi, out[1+N*N..]=C ----
  float* __restrict__ pi = out + 1;
  float* __restrict__ cm = out + 1 + (size_t)NPTS * NPTS;
  float uu[RPW];
#pragma unroll
  for (int r = 0; r < RPW; ++r) uu[r] = coh_load(u + row0 + r) * S_L2E;

  const int cb = wq * QCOLS + lane * 4;
  float costacc = 0.f;
#pragma unroll
  for (int jt = 0; jt < NJT; ++jt) {
    const int j = cb + jt * 256;
    const float4 W  = *(const float4*)(sW + j);
    const float4 C0 = *(const float4*)(sYc0 + j);
    const float4 C1 = *(const float4*)(sYc1 + j);
#pragma unroll
    for (int r = 0; r < RPW; ++r) {
      const float s0 = fabsf(rxu[r] - C0.x) + fabsf(ryu[r] - C1.x);
      const float s1 = fabsf(rxu[r] - C0.y) + fabsf(ryu[r] - C1.y);
      const float s2 = fabsf(rxu[r] - C0.z) + fabsf(ryu[r] - C1.z);
      const float s3 = fabsf(rxu[r] - C0.w) + fabsf(ryu[r] - C1.w);
      const float p0 = fexp2((uu[r] + W.x) - s0);
      const float p1 = fexp2((uu[r] + W.y) - s1);
      const float p2 = fexp2((uu[r] + W.z) - s2);
      const float p3 = fexp2((uu[r] + W.w) - s3);
      costacc = fmaf(p0, s0, costacc);
      costacc = fmaf(p1, s1, costacc);
      costacc = fmaf(p2, s2, costacc);
      costacc = fmaf(p3, s3, costacc);
      const size_t off = (size_t)(row0 + r) * NPTS + j;
      f4u pv; pv.x = p0; pv.y = p1; pv.z = p2; pv.w = p3;
      f4u cv; cv.x = s0 * INV_SL; cv.y = s1 * INV_SL;
      cv.z = s2 * INV_SL; cv.w = s3 * INV_SL;
      *(f4u*)(pi + off) = pv;   // out+1 base is 4B-aligned; f4u is aligned(4)
      *(f4u*)(cm + off) = cv;
    }
  }
  const float cw = wave_sum64(costacc);
  if (lane == 0) sCost[wv] = cw;
  __syncthreads();
  if (tid == 0) {
    float c = 0.f;
#pragma unroll
    for (int w = 0; w < WPB; ++w) c += sCost[w];
    atomicAdd(out, c * INV_SL);
  }
}

__global__ void sinkhorn_init(float* __restrict__ v, int* __restrict__ flags,
                              float* __restrict__ out) {
  const int i = blockIdx.x * blockDim.x + threadIdx.x;
  if (i < NPTS) coh_store(v + i, 0.f);
  if (i < NBLK) coh_store_i(flags + i, 0);
  if (i == 0) out[0] = 0.f;
}

extern "C" void kernel_launch(void* const* d_in, const int* in_sizes, int n_in,
                              void* d_out, int out_size, void* d_ws, size_t ws_size,
                              hipStream_t stream) {
  const float* x = (const float*)d_in[0];
  const float* y = (const float*)d_in[1];
  float* u = (float*)d_ws;
  float* v = u + NPTS;
  int* flags = (int*)(v + NPTS);
  float* out = (float*)d_out;

  sinkhorn_init<<<dim3(16), dim3(256), 0, stream>>>(v, flags, out);

  void* args[6];
  args[0] = (void*)&x;
  args[1] = (void*)&y;
  args[2] = (void*)&u;
  args[3] = (void*)&v;
  args[4] = (void*)&out;
  args[5] = (void*)&flags;
  hipLaunchCooperativeKernel((void*)sinkhorn_main, dim3(NBLK), dim3(TPB),
                             args, 0, stream);
}